// Round 7
// baseline (985.187 us; speedup 1.0000x reference)
//
#include <hip/hip_runtime.h>
#include <math.h>

#define NHEADS 16
#define HD 64
#define HID 1024
#define BATCH 4
#define SQ 16
#define SKV 8192
#define ROWS 64     // B*SQ
#define NCHUNK 32
#define CHUNK 256   // keys per attn block (64 per wave)
#define LN_EPS 1e-5f

// ---------------------------------------------------------------------------
// Kernel 1: q = RoPE(x @ wq^T + bq) -> [B][NH][SQ][HD]  (unchanged)
// ---------------------------------------------------------------------------
__global__ __launch_bounds__(256) void qrope_gemv(
    const float* __restrict__ x,
    const float* __restrict__ xm,
    const float* __restrict__ wq,
    const float* __restrict__ bq,
    float* __restrict__ qout)
{
    __shared__ float xs[ROWS * 256];
    __shared__ float sqx[4][ROWS];

    const int t = threadIdx.x, w = t >> 6, l = t & 63;
    const int cb = blockIdx.x;
    const int h = cb >> 4;
    const int sub = cb & 15;
    const int dd = sub * 2 + (w & 1) + (w >> 1) * 32;
    const int j = h * 64 + dd;

    float acc[ROWS];
    #pragma unroll
    for (int r = 0; r < ROWS; ++r) acc[r] = 0.f;

    const float4* x4 = (const float4*)x;
    const float4* w4 = (const float4*)(wq + (size_t)j * HID);
    float4* xs4 = (float4*)xs;

    for (int ck = 0; ck < 4; ++ck) {
        __syncthreads();
        #pragma unroll
        for (int p = 0; p < 16; ++p) {
            const int idx = t + p * 256;
            const int r = idx >> 6, c = idx & 63;
            xs4[idx] = x4[(size_t)r * 256 + ck * 64 + c];
        }
        __syncthreads();

        const float4 wf = w4[ck * 64 + l];
        #pragma unroll
        for (int r = 0; r < ROWS; ++r) {
            const float4 xf = xs4[r * 64 + l];
            acc[r] += wf.x * xf.x + wf.y * xf.y + wf.z * xf.z + wf.w * xf.w;
        }
    }

    #pragma unroll
    for (int r = 0; r < ROWS; ++r) {
        float a = acc[r];
        #pragma unroll
        for (int off = 32; off; off >>= 1) a += __shfl_xor(a, off);
        acc[r] = a;
    }
    float val = acc[0];
    #pragma unroll
    for (int r = 1; r < ROWS; ++r) val = (l == r) ? acc[r] : val;
    val += bq[j];

    sqx[w][l] = val;
    __syncthreads();

    const int r = l;
    float outv;
    if (w < 2) {
        const float q0 = sqx[w][l];
        const float q1 = sqx[w + 2][l];
        const float sn = xm[r * 64 + dd];
        const float co = xm[r * 64 + 32 + dd];
        outv = q0 * co - q1 * sn;
    } else {
        const int d2 = dd - 32;
        const float q0 = sqx[w - 2][l];
        const float q1 = sqx[w][l];
        const float sn = xm[r * 64 + d2];
        const float co = xm[r * 64 + 32 + d2];
        outv = q0 * sn + q1 * co;
    }
    const int b = r >> 4, s_ = r & 15;
    qout[(((size_t)b * NHEADS + h) * SQ + s_) * HD + dd] = outv;
}

// ---------------------------------------------------------------------------
// Kernel 2: split-K partial attention, lane = key (reduce-free QK).
// grid (NCHUNK, NH, B) = 2048 blocks, 256 threads (4 waves).
// Wave w owns keys [64w, 64w+64) of the chunk; lane l = key-in-wave.
//   QK: lane reads its K row (16 dwordx4), Q broadcast from LDS -> pure FMA.
//   Softmax: one-shot per row (all 64 scores present): 6-shfl max, 1 exp,
//            6-shfl sum. No online rescaling.
//   PV: p staged to per-wave LDS buffer (no barrier; same-wave ordering),
//       lane = dim, V coalesced from global.
// One LDS merge per block combines the 4 waves (p-buffer reused as oL).
// ---------------------------------------------------------------------------
__global__ __launch_bounds__(256, 2) void attn_partial(
    const float* __restrict__ q,     // [B][NH][SQ][HD]
    const float* __restrict__ kc,    // [B][NH][SKV][HD]
    const float* __restrict__ vc,    // [B][NH][SKV][HD]
    float* __restrict__ o_part,      // [B*NH][NCHUNK][SQ][HD]
    float* __restrict__ ml_part)     // [B*NH][NCHUNK][SQ][2]
{
    __shared__ float Qs[SQ][HD];     // 4 KB
    __shared__ float pL[4][SQ][HD];  // 16 KB: p-values, reused as per-wave O
    __shared__ float mL[4][SQ];      // 256 B
    __shared__ float lL[4][SQ];      // 256 B

    const int chunk = blockIdx.x, h = blockIdx.y, b = blockIdx.z;
    const int bh = b * NHEADS + h;
    const int t = threadIdx.x, w = t >> 6, l = t & 63;

    // ---- stage Q once
    ((float4*)Qs)[t] = ((const float4*)(q + (size_t)bh * SQ * HD))[t];
    __syncthreads();

    const size_t kvbase = (size_t)bh * SKV * HD + ((size_t)chunk * CHUNK + w * 64) * HD;
    const float4* kb = (const float4*)(kc + kvbase);
    const float* vb = vc + kvbase;

    // ---- QK: s[r] = K[key=l] . Q[r]  (lane = key, zero cross-lane reduces)
    float s[SQ];
    #pragma unroll
    for (int r = 0; r < SQ; ++r) s[r] = 0.f;

    #pragma unroll
    for (int j = 0; j < 16; ++j) {
        const float4 kj = kb[l * 16 + j];           // lane's K row, quad j
        #pragma unroll
        for (int r = 0; r < SQ; ++r) {
            const float4 q4 = *((const float4*)&Qs[r][j * 4]);  // uniform bcast
            s[r] += kj.x * q4.x + kj.y * q4.y + kj.z * q4.z + kj.w * q4.w;
        }
    }

    // ---- one-shot softmax per row (all 64 scores live across the wave)
    #pragma unroll
    for (int r = 0; r < SQ; ++r) {
        float mx = s[r];
        #pragma unroll
        for (int off = 1; off < 64; off <<= 1) mx = fmaxf(mx, __shfl_xor(mx, off));
        const float pe = __expf(s[r] - mx);
        float ls = pe;
        #pragma unroll
        for (int off = 1; off < 64; off <<= 1) ls += __shfl_xor(ls, off);
        pL[w][r][l] = pe;
        if (l == 0) { mL[w][r] = mx; lL[w][r] = ls; }
    }

    // ---- PV: lane = dim; p broadcast from LDS, V coalesced from global
    float oa[SQ];
    #pragma unroll
    for (int r = 0; r < SQ; ++r) oa[r] = 0.f;

    #pragma unroll
    for (int kq = 0; kq < 16; ++kq) {
        const float v0 = vb[(kq * 4 + 0) * HD + l];
        const float v1 = vb[(kq * 4 + 1) * HD + l];
        const float v2 = vb[(kq * 4 + 2) * HD + l];
        const float v3 = vb[(kq * 4 + 3) * HD + l];
        #pragma unroll
        for (int r = 0; r < SQ; ++r) {
            const float4 p4 = *((const float4*)&pL[w][r][kq * 4]);  // uniform
            oa[r] += p4.x * v0 + p4.y * v1 + p4.z * v2 + p4.w * v3;
        }
    }

    // ---- overwrite p-buffer with per-wave O (all pL reads above are done
    //      in-wave; LDS ordering within a wave is program-order)
    #pragma unroll
    for (int r = 0; r < SQ; ++r) pL[w][r][l] = oa[r];
    __syncthreads();

    // ---- merge the 4 waves: thread t -> (row r = t>>4, dim-quad dq = t&15)
    {
        const int r = t >> 4, dq = t & 15;
        const float M = fmaxf(fmaxf(mL[0][r], mL[1][r]), fmaxf(mL[2][r], mL[3][r]));
        float L = 0.f;
        float4 O = make_float4(0.f, 0.f, 0.f, 0.f);
        #pragma unroll
        for (int ww = 0; ww < 4; ++ww) {
            const float sc = __expf(mL[ww][r] - M);
            L += lL[ww][r] * sc;
            const float4 ov = *((const float4*)&pL[ww][r][dq * 4]);
            O.x += ov.x * sc; O.y += ov.y * sc; O.z += ov.z * sc; O.w += ov.w * sc;
        }
        ((float4*)(o_part + (((size_t)bh * NCHUNK + chunk) * SQ + r) * HD))[dq] = O;
        if (dq == 0) {
            ml_part[(((size_t)bh * NCHUNK + chunk) * SQ + r) * 2 + 0] = M;
            ml_part[(((size_t)bh * NCHUNK + chunk) * SQ + r) * 2 + 1] = L;
        }
    }
}

// ---------------------------------------------------------------------------
// Kernel 3: combine partials -> ctx [64][1024]  (unchanged)
// ---------------------------------------------------------------------------
__global__ __launch_bounds__(256) void attn_combine(
    const float* __restrict__ o_part,
    const float* __restrict__ ml_part,
    float* __restrict__ ctx)
{
    __shared__ float mls[NCHUNK * 4 * 2];
    const int bh = blockIdx.x >> 2, qg = blockIdx.x & 3;
    const int b = bh >> 4, h = bh & 15;
    const int t = threadIdx.x;
    const int qi_l = t >> 6, d = t & 63;
    const int qi = qg * 4 + qi_l;

    mls[t] = ml_part[(((size_t)bh * NCHUNK + (t >> 3)) * SQ + qg * 4 + ((t >> 1) & 3)) * 2 + (t & 1)];
    __syncthreads();

    float M = -INFINITY;
    #pragma unroll
    for (int c = 0; c < NCHUNK; ++c) M = fmaxf(M, mls[(c * 4 + qi_l) * 2]);
    float L = 0.f, O = 0.f;
    #pragma unroll 4
    for (int c = 0; c < NCHUNK; ++c) {
        const float sc = __expf(mls[(c * 4 + qi_l) * 2] - M);
        L += mls[(c * 4 + qi_l) * 2 + 1] * sc;
        O += o_part[(((size_t)bh * NCHUNK + c) * SQ + qi) * HD + d] * sc;
    }
    ctx[((size_t)(b * SQ + qi)) * HID + h * HD + d] = O / L;
}

// ---------------------------------------------------------------------------
// Kernel 4: y = x + ctx @ wo^T + bo  (unchanged)
// ---------------------------------------------------------------------------
__global__ __launch_bounds__(256) void out_gemv(
    const float* __restrict__ ctx,
    const float* __restrict__ x,
    const float* __restrict__ wo,
    const float* __restrict__ bo,
    float* __restrict__ y)
{
    __shared__ float xs[ROWS * 256];

    const int t = threadIdx.x, w = t >> 6, l = t & 63;
    const int j = blockIdx.x * 4 + w;

    float acc[ROWS];
    #pragma unroll
    for (int r = 0; r < ROWS; ++r) acc[r] = 0.f;

    const float4* c4 = (const float4*)ctx;
    const float4* w4 = (const float4*)(wo + (size_t)j * HID);
    float4* xs4 = (float4*)xs;

    for (int ck = 0; ck < 4; ++ck) {
        __syncthreads();
        #pragma unroll
        for (int p = 0; p < 16; ++p) {
            const int idx = t + p * 256;
            const int r = idx >> 6, c = idx & 63;
            xs4[idx] = c4[(size_t)r * 256 + ck * 64 + c];
        }
        __syncthreads();

        const float4 wf = w4[ck * 64 + l];
        #pragma unroll
        for (int r = 0; r < ROWS; ++r) {
            const float4 xf = xs4[r * 64 + l];
            acc[r] += wf.x * xf.x + wf.y * xf.y + wf.z * xf.z + wf.w * xf.w;
        }
    }

    #pragma unroll
    for (int r = 0; r < ROWS; ++r) {
        float a = acc[r];
        #pragma unroll
        for (int off = 32; off; off >>= 1) a += __shfl_xor(a, off);
        acc[r] = a;
    }
    float val = acc[0];
    #pragma unroll
    for (int r = 1; r < ROWS; ++r) val = (l == r) ? acc[r] : val;

    val += bo[j] + x[(size_t)l * HID + j];
    y[(size_t)l * HID + j] = val;
}

// ---------------------------------------------------------------------------
// Kernel 5: out = LN(y) * gamma + beta  (unchanged)
// ---------------------------------------------------------------------------
__global__ __launch_bounds__(256) void ln_kernel(
    const float* __restrict__ y,
    const float* __restrict__ gamma,
    const float* __restrict__ beta,
    float* __restrict__ out)
{
    __shared__ float red[8];
    const int r = blockIdx.x, t = threadIdx.x;
    const int w = t >> 6, l = t & 63;

    const float4 yv = ((const float4*)(y + (size_t)r * HID))[t];
    float sum = yv.x + yv.y + yv.z + yv.w;
    float ssq = yv.x * yv.x + yv.y * yv.y + yv.z * yv.z + yv.w * yv.w;
    #pragma unroll
    for (int off = 32; off; off >>= 1) {
        sum += __shfl_xor(sum, off);
        ssq += __shfl_xor(ssq, off);
    }
    if (l == 0) { red[w] = sum; red[4 + w] = ssq; }
    __syncthreads();
    sum = red[0] + red[1] + red[2] + red[3];
    ssq = red[4] + red[5] + red[6] + red[7];
    const float mu = sum * (1.f / HID);
    const float var = ssq * (1.f / HID) - mu * mu;
    const float rstd = rsqrtf(var + LN_EPS);

    const float4 g = ((const float4*)gamma)[t];
    const float4 be = ((const float4*)beta)[t];
    float4 o;
    o.x = (yv.x - mu) * rstd * g.x + be.x;
    o.y = (yv.y - mu) * rstd * g.y + be.y;
    o.z = (yv.z - mu) * rstd * g.z + be.z;
    o.w = (yv.w - mu) * rstd * g.w + be.w;
    ((float4*)(out + (size_t)r * HID))[t] = o;
}

// ---------------------------------------------------------------------------
extern "C" void kernel_launch(void* const* d_in, const int* in_sizes, int n_in,
                              void* d_out, int out_size, void* d_ws, size_t ws_size,
                              hipStream_t stream) {
    const float* x     = (const float*)d_in[0];
    const float* xm    = (const float*)d_in[1];
    const float* kc    = (const float*)d_in[2];
    const float* vc    = (const float*)d_in[3];
    const float* wq    = (const float*)d_in[4];
    const float* bq    = (const float*)d_in[5];
    const float* wo    = (const float*)d_in[6];
    const float* bo    = (const float*)d_in[7];
    const float* gamma = (const float*)d_in[8];
    const float* beta  = (const float*)d_in[9];
    float* out = (float*)d_out;

    float* ws = (float*)d_ws;
    float* q_ws   = ws;                                               // 65536
    float* o_ws   = q_ws + ROWS * HID;                                // 2097152
    float* ml_ws  = o_ws + (size_t)BATCH * NHEADS * NCHUNK * SQ * HD; // 65536
    float* ctx_ws = ml_ws + BATCH * NHEADS * NCHUNK * SQ * 2;         // 65536
    float* y_ws   = ctx_ws + ROWS * HID;                              // 65536

    qrope_gemv<<<dim3(256), 256, 0, stream>>>(x, xm, wq, bq, q_ws);
    attn_partial<<<dim3(NCHUNK, NHEADS, BATCH), 256, 0, stream>>>(q_ws, kc, vc, o_ws, ml_ws);
    attn_combine<<<dim3(256), 256, 0, stream>>>(o_ws, ml_ws, ctx_ws);
    out_gemv<<<dim3(256), 256, 0, stream>>>(ctx_ws, x, wo, bo, y_ws);
    ln_kernel<<<dim3(ROWS), 256, 0, stream>>>(y_ws, gamma, beta, out);
}

// Round 8
// 181.440 us; speedup vs baseline: 5.4298x; 5.4298x over previous
//
#include <hip/hip_runtime.h>
#include <math.h>

#define NHEADS 16
#define HD 64
#define HID 1024
#define BATCH 4
#define SQ 16
#define SKV 8192
#define ROWS 64     // B*SQ
#define NCHUNK 32
#define CHUNK 256   // keys per attn block (64 per wave)
#define LN_EPS 1e-5f

typedef _Float16 half4v __attribute__((ext_vector_type(4)));
typedef _Float16 half8v __attribute__((ext_vector_type(8)));
typedef float f32x4 __attribute__((ext_vector_type(4)));

// ---------------------------------------------------------------------------
// DPP row reduce over 16-lane rows (sum / max). All 16 lanes get the result.
// ---------------------------------------------------------------------------
__device__ __forceinline__ float rowsum16(float x) {
    union fi { float f; int i; };
    fi a, b;
    a.f = x;
    b.i = __builtin_amdgcn_update_dpp(0, a.i, 0x128, 0xf, 0xf, true); a.f += b.f;
    b.i = __builtin_amdgcn_update_dpp(0, a.i, 0x124, 0xf, 0xf, true); a.f += b.f;
    b.i = __builtin_amdgcn_update_dpp(0, a.i, 0x122, 0xf, 0xf, true); a.f += b.f;
    b.i = __builtin_amdgcn_update_dpp(0, a.i, 0x121, 0xf, 0xf, true); a.f += b.f;
    return a.f;
}
__device__ __forceinline__ float rowmax16(float x) {
    union fi { float f; int i; };
    fi a, b;
    a.f = x;
    b.i = __builtin_amdgcn_update_dpp(0, a.i, 0x128, 0xf, 0xf, true); a.f = fmaxf(a.f, b.f);
    b.i = __builtin_amdgcn_update_dpp(0, a.i, 0x124, 0xf, 0xf, true); a.f = fmaxf(a.f, b.f);
    b.i = __builtin_amdgcn_update_dpp(0, a.i, 0x122, 0xf, 0xf, true); a.f = fmaxf(a.f, b.f);
    b.i = __builtin_amdgcn_update_dpp(0, a.i, 0x121, 0xf, 0xf, true); a.f = fmaxf(a.f, b.f);
    return a.f;
}

// ---------------------------------------------------------------------------
// Kernel 1: q = RoPE(x @ wq^T + bq) -> [B][NH][SQ][HD]  (unchanged)
// ---------------------------------------------------------------------------
__global__ __launch_bounds__(256) void qrope_gemv(
    const float* __restrict__ x,
    const float* __restrict__ xm,
    const float* __restrict__ wq,
    const float* __restrict__ bq,
    float* __restrict__ qout)
{
    __shared__ float xs[ROWS * 256];
    __shared__ float sqx[4][ROWS];

    const int t = threadIdx.x, w = t >> 6, l = t & 63;
    const int cb = blockIdx.x;
    const int h = cb >> 4;
    const int sub = cb & 15;
    const int dd = sub * 2 + (w & 1) + (w >> 1) * 32;
    const int j = h * 64 + dd;

    float acc[ROWS];
    #pragma unroll
    for (int r = 0; r < ROWS; ++r) acc[r] = 0.f;

    const float4* x4 = (const float4*)x;
    const float4* w4 = (const float4*)(wq + (size_t)j * HID);
    float4* xs4 = (float4*)xs;

    for (int ck = 0; ck < 4; ++ck) {
        __syncthreads();
        #pragma unroll
        for (int p = 0; p < 16; ++p) {
            const int idx = t + p * 256;
            const int r = idx >> 6, c = idx & 63;
            xs4[idx] = x4[(size_t)r * 256 + ck * 64 + c];
        }
        __syncthreads();

        const float4 wf = w4[ck * 64 + l];
        #pragma unroll
        for (int r = 0; r < ROWS; ++r) {
            const float4 xf = xs4[r * 64 + l];
            acc[r] += wf.x * xf.x + wf.y * xf.y + wf.z * xf.z + wf.w * xf.w;
        }
    }

    #pragma unroll
    for (int r = 0; r < ROWS; ++r) {
        float a = acc[r];
        #pragma unroll
        for (int off = 32; off; off >>= 1) a += __shfl_xor(a, off);
        acc[r] = a;
    }
    float val = acc[0];
    #pragma unroll
    for (int r = 1; r < ROWS; ++r) val = (l == r) ? acc[r] : val;
    val += bq[j];

    sqx[w][l] = val;
    __syncthreads();

    const int r = l;
    float outv;
    if (w < 2) {
        const float q0 = sqx[w][l];
        const float q1 = sqx[w + 2][l];
        const float sn = xm[r * 64 + dd];
        const float co = xm[r * 64 + 32 + dd];
        outv = q0 * co - q1 * sn;
    } else {
        const int d2 = dd - 32;
        const float q0 = sqx[w - 2][l];
        const float q1 = sqx[w][l];
        const float sn = xm[r * 64 + d2];
        const float co = xm[r * 64 + 32 + d2];
        outv = q0 * sn + q1 * co;
    }
    const int b = r >> 4, s_ = r & 15;
    qout[(((size_t)b * NHEADS + h) * SQ + s_) * HD + dd] = outv;
}

// ---------------------------------------------------------------------------
// Kernel 2: split-K partial attention with MFMA QK^T.
// grid (NCHUNK, NH, B) = 2048 blocks, 256 threads (4 waves).
// Wave w owns keys [64w, 64w+64): 4 tiles of 16 keys.
//   QK: K tile staged to per-wave LDS as f16 (XOR-swizzled rows), Q staged
//       once as f16; frags = single ds_read_b128 each; 2 mfma/tile.
//       D-layout: key = lane&15, q-row = (lane>>4)*4 + reg   [m89-verified]
//   Softmax: one-shot over wave's 64 keys; DPP row-reduce; 16 exps/lane.
//   PV: p via LDS [16][68] f32; lane=(kg=l>>4 keys, dq=l&15 dim-quad);
//       V coalesced dwordx4 from global; shfl kg-reduce; LDS merge of 4 waves.
// ---------------------------------------------------------------------------
__global__ __launch_bounds__(256, 2) void attn_partial(
    const float* __restrict__ q,     // [B][NH][SQ][HD]
    const float* __restrict__ kc,    // [B][NH][SKV][HD]
    const float* __restrict__ vc,    // [B][NH][SKV][HD]
    float* __restrict__ o_part,      // [B*NH][NCHUNK][SQ][HD]
    float* __restrict__ ml_part)     // [B*NH][NCHUNK][SQ][2]
{
    __shared__ _Float16 Qs[SQ * HD];        // 2 KB, swizzled f16
    __shared__ _Float16 Ks[4][16 * HD];     // 8 KB, per-wave K tile, swizzled
    __shared__ float pL[4][SQ][68];         // 17.4 KB: p, then per-wave O
    __shared__ float mL[4][SQ];
    __shared__ float lL[4][SQ];

    const int chunk = blockIdx.x, h = blockIdx.y, b = blockIdx.z;
    const int bh = b * NHEADS + h;
    const int t = threadIdx.x, w = t >> 6, l = t & 63;
    const int lo = l & 15, g = l >> 4;

    // ---- stage Q (f32 -> f16, swizzled): thread t handles float4 #t
    {
        const float4 qv = ((const float4*)(q + (size_t)bh * SQ * HD))[t];
        const int row = t >> 4, c4 = t & 15;
        const int idx = (row * 64 + c4 * 4) ^ ((row & 7) << 3);
        half4v hv = { (_Float16)qv.x, (_Float16)qv.y, (_Float16)qv.z, (_Float16)qv.w };
        *(half4v*)&Qs[idx] = hv;
    }
    __syncthreads();

    const size_t kvbase = (size_t)bh * SKV * HD + ((size_t)chunk * CHUNK + w * 64) * HD;
    const float4* kb = (const float4*)(kc + kvbase);
    const float* vb = vc + kvbase;

    // ---- A-frags (Q), constant across key tiles: k-slice = kk*32 + g*8
    half8v aF[2];
    #pragma unroll
    for (int kk = 0; kk < 2; ++kk) {
        const int idx = (lo * 64 + kk * 32 + g * 8) ^ ((lo & 7) << 3);
        aF[kk] = *(const half8v*)&Qs[idx];
    }

    // ---- QK^T per 16-key tile
    f32x4 S[4];
    #pragma unroll
    for (int tile = 0; tile < 4; ++tile) {
        #pragma unroll
        for (int qd = 0; qd < 4; ++qd) {
            const int fidx = qd * 64 + l;               // float4 index in tile
            const float4 kv = kb[tile * 256 + fidx];    // coalesced
            const int row = fidx >> 4, c4 = fidx & 15;
            const int idx = (row * 64 + c4 * 4) ^ ((row & 7) << 3);
            half4v hv = { (_Float16)kv.x, (_Float16)kv.y, (_Float16)kv.z, (_Float16)kv.w };
            *(half4v*)&Ks[w][idx] = hv;
        }
        // same-wave LDS write->read ordering; no barrier needed
        f32x4 acc = {0.f, 0.f, 0.f, 0.f};
        #pragma unroll
        for (int kk = 0; kk < 2; ++kk) {
            const int idx = (lo * 64 + kk * 32 + g * 8) ^ ((lo & 7) << 3);
            const half8v bF = *(const half8v*)&Ks[w][idx];
            acc = __builtin_amdgcn_mfma_f32_16x16x32_f16(aF[kk], bF, acc, 0, 0, 0);
        }
        S[tile] = acc;
    }

    // ---- one-shot softmax over the wave's 64 keys
    // lane holds scores for key = tile*16 + lo, rows g*4 + reg
    float mrow[4], lrow[4];
    #pragma unroll
    for (int reg = 0; reg < 4; ++reg) {
        float mx = fmaxf(fmaxf(S[0][reg], S[1][reg]), fmaxf(S[2][reg], S[3][reg]));
        mrow[reg] = rowmax16(mx);
    }
    #pragma unroll
    for (int reg = 0; reg < 4; ++reg) {
        const int row = g * 4 + reg;
        float ls = 0.f;
        #pragma unroll
        for (int tile = 0; tile < 4; ++tile) {
            const float pe = __expf(S[tile][reg] - mrow[reg]);
            pL[w][row][tile * 16 + lo] = pe;
            ls += pe;
        }
        lrow[reg] = rowsum16(ls);
    }
    if (lo == 0) {
        #pragma unroll
        for (int reg = 0; reg < 4; ++reg) {
            mL[w][g * 4 + reg] = mrow[reg];
            lL[w][g * 4 + reg] = lrow[reg];
        }
    }

    // ---- PV: lane g owns keys g*16..g*16+15; lane lo = dim-quad
    f32x4 oacc[SQ];
    #pragma unroll
    for (int r = 0; r < SQ; ++r) oacc[r] = (f32x4){0.f, 0.f, 0.f, 0.f};

    #pragma unroll
    for (int k4 = 0; k4 < 4; ++k4) {
        float4 vv[4];
        #pragma unroll
        for (int j = 0; j < 4; ++j)
            vv[j] = ((const float4*)(vb + (size_t)(g * 16 + k4 * 4 + j) * HD))[lo];
        #pragma unroll
        for (int r = 0; r < SQ; ++r) {
            const f32x4 p4 = *(const f32x4*)&pL[w][r][g * 16 + k4 * 4];
            oacc[r][0] += p4[0] * vv[0].x + p4[1] * vv[1].x + p4[2] * vv[2].x + p4[3] * vv[3].x;
            oacc[r][1] += p4[0] * vv[0].y + p4[1] * vv[1].y + p4[2] * vv[2].y + p4[3] * vv[3].y;
            oacc[r][2] += p4[0] * vv[0].z + p4[1] * vv[1].z + p4[2] * vv[2].z + p4[3] * vv[3].z;
            oacc[r][3] += p4[0] * vv[0].w + p4[1] * vv[1].w + p4[2] * vv[2].w + p4[3] * vv[3].w;
        }
    }

    // ---- reduce over the 4 key-groups (lane bits 4,5)
    #pragma unroll
    for (int r = 0; r < SQ; ++r) {
        #pragma unroll
        for (int off = 16; off <= 32; off <<= 1) {
            oacc[r][0] += __shfl_xor(oacc[r][0], off);
            oacc[r][1] += __shfl_xor(oacc[r][1], off);
            oacc[r][2] += __shfl_xor(oacc[r][2], off);
            oacc[r][3] += __shfl_xor(oacc[r][3], off);
        }
    }

    // ---- overwrite pL with per-wave O (all pL reads above are in-wave)
    if (g == 0) {
        #pragma unroll
        for (int r = 0; r < SQ; ++r)
            *(f32x4*)&pL[w][r][lo * 4] = oacc[r];
    }
    __syncthreads();

    // ---- merge 4 waves: thread t -> (row r = t>>4, dim-quad dq = t&15)
    {
        const int r = t >> 4, dq = t & 15;
        const float M = fmaxf(fmaxf(mL[0][r], mL[1][r]), fmaxf(mL[2][r], mL[3][r]));
        float L = 0.f;
        f32x4 O = (f32x4){0.f, 0.f, 0.f, 0.f};
        #pragma unroll
        for (int ww = 0; ww < 4; ++ww) {
            const float sc = __expf(mL[ww][r] - M);
            L += lL[ww][r] * sc;
            const f32x4 ov = *(const f32x4*)&pL[ww][r][dq * 4];
            O[0] += ov[0] * sc; O[1] += ov[1] * sc; O[2] += ov[2] * sc; O[3] += ov[3] * sc;
        }
        *(f32x4*)(o_part + (((size_t)bh * NCHUNK + chunk) * SQ + r) * HD + dq * 4) = O;
        if (dq == 0) {
            ml_part[(((size_t)bh * NCHUNK + chunk) * SQ + r) * 2 + 0] = M;
            ml_part[(((size_t)bh * NCHUNK + chunk) * SQ + r) * 2 + 1] = L;
        }
    }
}

// ---------------------------------------------------------------------------
// Kernel 3: combine partials -> ctx [64][1024]  (unchanged)
// ---------------------------------------------------------------------------
__global__ __launch_bounds__(256) void attn_combine(
    const float* __restrict__ o_part,
    const float* __restrict__ ml_part,
    float* __restrict__ ctx)
{
    __shared__ float mls[NCHUNK * 4 * 2];
    const int bh = blockIdx.x >> 2, qg = blockIdx.x & 3;
    const int b = bh >> 4, h = bh & 15;
    const int t = threadIdx.x;
    const int qi_l = t >> 6, d = t & 63;
    const int qi = qg * 4 + qi_l;

    mls[t] = ml_part[(((size_t)bh * NCHUNK + (t >> 3)) * SQ + qg * 4 + ((t >> 1) & 3)) * 2 + (t & 1)];
    __syncthreads();

    float M = -INFINITY;
    #pragma unroll
    for (int c = 0; c < NCHUNK; ++c) M = fmaxf(M, mls[(c * 4 + qi_l) * 2]);
    float L = 0.f, O = 0.f;
    #pragma unroll 4
    for (int c = 0; c < NCHUNK; ++c) {
        const float sc = __expf(mls[(c * 4 + qi_l) * 2] - M);
        L += mls[(c * 4 + qi_l) * 2 + 1] * sc;
        O += o_part[(((size_t)bh * NCHUNK + c) * SQ + qi) * HD + d] * sc;
    }
    ctx[((size_t)(b * SQ + qi)) * HID + h * HD + d] = O / L;
}

// ---------------------------------------------------------------------------
// Kernel 4: y = x + ctx @ wo^T + bo  (unchanged)
// ---------------------------------------------------------------------------
__global__ __launch_bounds__(256) void out_gemv(
    const float* __restrict__ ctx,
    const float* __restrict__ x,
    const float* __restrict__ wo,
    const float* __restrict__ bo,
    float* __restrict__ y)
{
    __shared__ float xs[ROWS * 256];

    const int t = threadIdx.x, w = t >> 6, l = t & 63;
    const int j = blockIdx.x * 4 + w;

    float acc[ROWS];
    #pragma unroll
    for (int r = 0; r < ROWS; ++r) acc[r] = 0.f;

    const float4* c4 = (const float4*)ctx;
    const float4* w4 = (const float4*)(wo + (size_t)j * HID);
    float4* xs4 = (float4*)xs;

    for (int ck = 0; ck < 4; ++ck) {
        __syncthreads();
        #pragma unroll
        for (int p = 0; p < 16; ++p) {
            const int idx = t + p * 256;
            const int r = idx >> 6, c = idx & 63;
            xs4[idx] = c4[(size_t)r * 256 + ck * 64 + c];
        }
        __syncthreads();

        const float4 wf = w4[ck * 64 + l];
        #pragma unroll
        for (int r = 0; r < ROWS; ++r) {
            const float4 xf = xs4[r * 64 + l];
            acc[r] += wf.x * xf.x + wf.y * xf.y + wf.z * xf.z + wf.w * xf.w;
        }
    }

    #pragma unroll
    for (int r = 0; r < ROWS; ++r) {
        float a = acc[r];
        #pragma unroll
        for (int off = 32; off; off >>= 1) a += __shfl_xor(a, off);
        acc[r] = a;
    }
    float val = acc[0];
    #pragma unroll
    for (int r = 1; r < ROWS; ++r) val = (l == r) ? acc[r] : val;

    val += bo[j] + x[(size_t)l * HID + j];
    y[(size_t)l * HID + j] = val;
}

// ---------------------------------------------------------------------------
// Kernel 5: out = LN(y) * gamma + beta  (unchanged)
// ---------------------------------------------------------------------------
__global__ __launch_bounds__(256) void ln_kernel(
    const float* __restrict__ y,
    const float* __restrict__ gamma,
    const float* __restrict__ beta,
    float* __restrict__ out)
{
    __shared__ float red[8];
    const int r = blockIdx.x, t = threadIdx.x;
    const int w = t >> 6, l = t & 63;

    const float4 yv = ((const float4*)(y + (size_t)r * HID))[t];
    float sum = yv.x + yv.y + yv.z + yv.w;
    float ssq = yv.x * yv.x + yv.y * yv.y + yv.z * yv.z + yv.w * yv.w;
    #pragma unroll
    for (int off = 32; off; off >>= 1) {
        sum += __shfl_xor(sum, off);
        ssq += __shfl_xor(ssq, off);
    }
    if (l == 0) { red[w] = sum; red[4 + w] = ssq; }
    __syncthreads();
    sum = red[0] + red[1] + red[2] + red[3];
    ssq = red[4] + red[5] + red[6] + red[7];
    const float mu = sum * (1.f / HID);
    const float var = ssq * (1.f / HID) - mu * mu;
    const float rstd = rsqrtf(var + LN_EPS);

    const float4 g = ((const float4*)gamma)[t];
    const float4 be = ((const float4*)beta)[t];
    float4 o;
    o.x = (yv.x - mu) * rstd * g.x + be.x;
    o.y = (yv.y - mu) * rstd * g.y + be.y;
    o.z = (yv.z - mu) * rstd * g.z + be.z;
    o.w = (yv.w - mu) * rstd * g.w + be.w;
    ((float4*)(out + (size_t)r * HID))[t] = o;
}

// ---------------------------------------------------------------------------
extern "C" void kernel_launch(void* const* d_in, const int* in_sizes, int n_in,
                              void* d_out, int out_size, void* d_ws, size_t ws_size,
                              hipStream_t stream) {
    const float* x     = (const float*)d_in[0];
    const float* xm    = (const float*)d_in[1];
    const float* kc    = (const float*)d_in[2];
    const float* vc    = (const float*)d_in[3];
    const float* wq    = (const float*)d_in[4];
    const float* bq    = (const float*)d_in[5];
    const float* wo    = (const float*)d_in[6];
    const float* bo    = (const float*)d_in[7];
    const float* gamma = (const float*)d_in[8];
    const float* beta  = (const float*)d_in[9];
    float* out = (float*)d_out;

    float* ws = (float*)d_ws;
    float* q_ws   = ws;                                               // 65536
    float* o_ws   = q_ws + ROWS * HID;                                // 2097152
    float* ml_ws  = o_ws + (size_t)BATCH * NHEADS * NCHUNK * SQ * HD; // 65536
    float* ctx_ws = ml_ws + BATCH * NHEADS * NCHUNK * SQ * 2;         // 65536
    float* y_ws   = ctx_ws + ROWS * HID;                              // 65536

    qrope_gemv<<<dim3(256), 256, 0, stream>>>(x, xm, wq, bq, q_ws);
    attn_partial<<<dim3(NCHUNK, NHEADS, BATCH), 256, 0, stream>>>(q_ws, kc, vc, o_ws, ml_ws);
    attn_combine<<<dim3(256), 256, 0, stream>>>(o_ws, ml_ws, ctx_ws);
    out_gemv<<<dim3(256), 256, 0, stream>>>(ctx_ws, x, wo, bo, y_ws);
    ln_kernel<<<dim3(ROWS), 256, 0, stream>>>(y_ws, gamma, beta, out);
}

// Round 9
// 116.076 us; speedup vs baseline: 8.4875x; 1.5631x over previous
//
#include <hip/hip_runtime.h>
#include <math.h>

#define NHEADS 16
#define HD 64
#define HID 1024
#define BATCH 4
#define SQ 16
#define SKV 8192
#define ROWS 64     // B*SQ
#define NCHUNK 32
#define CHUNK 256   // keys per attn block (64 per wave)
#define LN_EPS 1e-5f

typedef _Float16 half4v __attribute__((ext_vector_type(4)));
typedef _Float16 half8v __attribute__((ext_vector_type(8)));
typedef float f32x4 __attribute__((ext_vector_type(4)));

// ---------------------------------------------------------------------------
// Kernel 1: q = RoPE(x @ wq^T + bq) -> [B][NH][SQ][HD]  (unchanged)
// ---------------------------------------------------------------------------
__global__ __launch_bounds__(256) void qrope_gemv(
    const float* __restrict__ x,
    const float* __restrict__ xm,
    const float* __restrict__ wq,
    const float* __restrict__ bq,
    float* __restrict__ qout)
{
    __shared__ float xs[ROWS * 256];
    __shared__ float sqx[4][ROWS];

    const int t = threadIdx.x, w = t >> 6, l = t & 63;
    const int cb = blockIdx.x;
    const int h = cb >> 4;
    const int sub = cb & 15;
    const int dd = sub * 2 + (w & 1) + (w >> 1) * 32;
    const int j = h * 64 + dd;

    float acc[ROWS];
    #pragma unroll
    for (int r = 0; r < ROWS; ++r) acc[r] = 0.f;

    const float4* x4 = (const float4*)x;
    const float4* w4 = (const float4*)(wq + (size_t)j * HID);
    float4* xs4 = (float4*)xs;

    for (int ck = 0; ck < 4; ++ck) {
        __syncthreads();
        #pragma unroll
        for (int p = 0; p < 16; ++p) {
            const int idx = t + p * 256;
            const int r = idx >> 6, c = idx & 63;
            xs4[idx] = x4[(size_t)r * 256 + ck * 64 + c];
        }
        __syncthreads();

        const float4 wf = w4[ck * 64 + l];
        #pragma unroll
        for (int r = 0; r < ROWS; ++r) {
            const float4 xf = xs4[r * 64 + l];
            acc[r] += wf.x * xf.x + wf.y * xf.y + wf.z * xf.z + wf.w * xf.w;
        }
    }

    #pragma unroll
    for (int r = 0; r < ROWS; ++r) {
        float a = acc[r];
        #pragma unroll
        for (int off = 32; off; off >>= 1) a += __shfl_xor(a, off);
        acc[r] = a;
    }
    float val = acc[0];
    #pragma unroll
    for (int r = 1; r < ROWS; ++r) val = (l == r) ? acc[r] : val;
    val += bq[j];

    sqx[w][l] = val;
    __syncthreads();

    const int r = l;
    float outv;
    if (w < 2) {
        const float q0 = sqx[w][l];
        const float q1 = sqx[w + 2][l];
        const float sn = xm[r * 64 + dd];
        const float co = xm[r * 64 + 32 + dd];
        outv = q0 * co - q1 * sn;
    } else {
        const int d2 = dd - 32;
        const float q0 = sqx[w - 2][l];
        const float q1 = sqx[w][l];
        const float sn = xm[r * 64 + d2];
        const float co = xm[r * 64 + 32 + d2];
        outv = q0 * sn + q1 * co;
    }
    const int b = r >> 4, s_ = r & 15;
    qout[(((size_t)b * NHEADS + h) * SQ + s_) * HD + dd] = outv;
}

// ---------------------------------------------------------------------------
// Kernel 2: split-K partial attention; swapped-operand MFMA QK^T, VALU PV.
// grid (NCHUNK, NH, B) = 2048 blocks, 256 threads (4 independent waves).
// Wave w owns keys [64w, 64w+64). Barrier-free until the 4-wave merge.
//   - K tile (64x64) staged whole: 16 coalesced float4 loads -> f16 LDS,
//     XOR swizzle (byte ^= (row&7)<<4); frags via single ds_read_b128.
//   - Q B-frags built from global directly (L2-resident, per-wave).
//   - S^T = mfma(K, Q): lane(g,lo): q=lo, key=kg*16+g*4+reg  [m89 layout]
//   - one-shot softmax: in-lane over 16 keys + shfl_xor(16,32); 16 exps/lane.
//   - PV on VALU: p via in-wave LDS broadcast, V coalesced from global.
// ---------------------------------------------------------------------------
__global__ __launch_bounds__(256, 2) void attn_partial(
    const float* __restrict__ q,     // [B][NH][SQ][HD]
    const float* __restrict__ kc,    // [B][NH][SKV][HD]
    const float* __restrict__ vc,    // [B][NH][SKV][HD]
    float* __restrict__ o_part,      // [B*NH][NCHUNK][SQ][HD]
    float* __restrict__ ml_part)     // [B*NH][NCHUNK][SQ][2]
{
    __shared__ _Float16 Ks[4][64 * 64];   // 32 KB: per-wave K tile, swizzled
    __shared__ float pL[4][SQ][68];       // 17.4 KB: p, then per-wave O
    __shared__ float mL[4][SQ];
    __shared__ float lL[4][SQ];

    const int chunk = blockIdx.x, h = blockIdx.y, b = blockIdx.z;
    const int bh = b * NHEADS + h;
    const int t = threadIdx.x, w = t >> 6, l = t & 63;
    const int lo = l & 15, g = l >> 4;

    const size_t kvbase = (size_t)bh * SKV * HD + ((size_t)chunk * CHUNK + w * 64) * HD;
    const float4* kb = (const float4*)(kc + kvbase);
    const float* vb = vc + kvbase;
    const float* qb = q + (size_t)bh * SQ * HD;

    // ---- stage the wave's whole K tile (64 keys x 64 dims) f32 -> f16 LDS
    _Float16* ks = Ks[w];
    #pragma unroll
    for (int p = 0; p < 16; ++p) {
        const int fidx = p * 64 + l;          // float4 index; coalesced 1KB/instr
        const float4 kv = kb[fidx];
        const int row = fidx >> 4, c4 = fidx & 15;
        const int byteoff = (row * 128 + c4 * 8) ^ ((row & 7) << 4);
        half4v hv = { (_Float16)kv.x, (_Float16)kv.y, (_Float16)kv.z, (_Float16)kv.w };
        *(half4v*)((char*)ks + byteoff) = hv;
    }

    // ---- Q B-frags direct from global: lane(g,lo) needs Q[q=lo][kk*32+g*8 ..+7]
    half8v bQ[2];
    #pragma unroll
    for (int kk = 0; kk < 2; ++kk) {
        const float4 qa = *(const float4*)(qb + lo * HD + kk * 32 + g * 8);
        const float4 qc = *(const float4*)(qb + lo * HD + kk * 32 + g * 8 + 4);
        bQ[kk] = (half8v){ (_Float16)qa.x, (_Float16)qa.y, (_Float16)qa.z, (_Float16)qa.w,
                           (_Float16)qc.x, (_Float16)qc.y, (_Float16)qc.z, (_Float16)qc.w };
    }

    // ---- QK^T swapped: S^T[key][q]; acc[kg]: lane(g,lo) q=lo, key=kg*16+g*4+reg
    f32x4 S[4];
    #pragma unroll
    for (int kg = 0; kg < 4; ++kg) {
        f32x4 acc = {0.f, 0.f, 0.f, 0.f};
        #pragma unroll
        for (int kk = 0; kk < 2; ++kk) {
            const int row = kg * 16 + lo;
            const int byteoff = (row * 128 + kk * 64 + g * 16) ^ ((row & 7) << 4);
            const half8v aK = *(const half8v*)((const char*)ks + byteoff);
            acc = __builtin_amdgcn_mfma_f32_16x16x32_f16(aK, bQ[kk], acc, 0, 0, 0);
        }
        S[kg] = acc;
    }

    // ---- one-shot softmax for q=lo over the wave's 64 keys
    float mx = S[0][0];
    #pragma unroll
    for (int kg = 0; kg < 4; ++kg)
        #pragma unroll
        for (int r = 0; r < 4; ++r) mx = fmaxf(mx, S[kg][r]);
    mx = fmaxf(mx, __shfl_xor(mx, 16));
    mx = fmaxf(mx, __shfl_xor(mx, 32));

    float ls = 0.f;
    #pragma unroll
    for (int kg = 0; kg < 4; ++kg) {
        #pragma unroll
        for (int r = 0; r < 4; ++r) {
            const float pe = __expf(S[kg][r] - mx);
            ls += pe;
            pL[w][lo][kg * 16 + g * 4 + r] = pe;   // in-wave LDS, no barrier
        }
    }
    ls += __shfl_xor(ls, 16);
    ls += __shfl_xor(ls, 32);
    if (g == 0) { mL[w][lo] = mx; lL[w][lo] = ls; }

    // ---- PV on VALU: lane(g,lo): keys g*16..+15, dims lo*4..+3
    f32x4 oacc[SQ];
    #pragma unroll
    for (int r = 0; r < SQ; ++r) oacc[r] = (f32x4){0.f, 0.f, 0.f, 0.f};

    #pragma unroll
    for (int k4 = 0; k4 < 4; ++k4) {
        float4 vv[4];
        #pragma unroll
        for (int j = 0; j < 4; ++j)
            vv[j] = *(const float4*)(vb + (size_t)(g * 16 + k4 * 4 + j) * HD + lo * 4);
        #pragma unroll
        for (int r = 0; r < SQ; ++r) {
            const f32x4 p4 = *(const f32x4*)&pL[w][r][g * 16 + k4 * 4];
            oacc[r][0] += p4[0] * vv[0].x + p4[1] * vv[1].x + p4[2] * vv[2].x + p4[3] * vv[3].x;
            oacc[r][1] += p4[0] * vv[0].y + p4[1] * vv[1].y + p4[2] * vv[2].y + p4[3] * vv[3].y;
            oacc[r][2] += p4[0] * vv[0].z + p4[1] * vv[1].z + p4[2] * vv[2].z + p4[3] * vv[3].z;
            oacc[r][3] += p4[0] * vv[0].w + p4[1] * vv[1].w + p4[2] * vv[2].w + p4[3] * vv[3].w;
        }
    }

    // ---- reduce over the 4 key-groups (lane bits 4,5)
    #pragma unroll
    for (int r = 0; r < SQ; ++r) {
        #pragma unroll
        for (int off = 16; off <= 32; off <<= 1) {
            oacc[r][0] += __shfl_xor(oacc[r][0], off);
            oacc[r][1] += __shfl_xor(oacc[r][1], off);
            oacc[r][2] += __shfl_xor(oacc[r][2], off);
            oacc[r][3] += __shfl_xor(oacc[r][3], off);
        }
    }

    // ---- overwrite pL with per-wave O (all pL reads above were in-wave)
    if (g == 0) {
        #pragma unroll
        for (int r = 0; r < SQ; ++r)
            *(f32x4*)&pL[w][r][lo * 4] = oacc[r];
    }
    __syncthreads();

    // ---- merge 4 waves: thread t -> (row r = t>>4, dim-quad dq = t&15)
    {
        const int r = t >> 4, dq = t & 15;
        const float M = fmaxf(fmaxf(mL[0][r], mL[1][r]), fmaxf(mL[2][r], mL[3][r]));
        float L = 0.f;
        f32x4 O = (f32x4){0.f, 0.f, 0.f, 0.f};
        #pragma unroll
        for (int ww = 0; ww < 4; ++ww) {
            const float sc = __expf(mL[ww][r] - M);
            L += lL[ww][r] * sc;
            const f32x4 ov = *(const f32x4*)&pL[ww][r][dq * 4];
            O[0] += ov[0] * sc; O[1] += ov[1] * sc; O[2] += ov[2] * sc; O[3] += ov[3] * sc;
        }
        *(f32x4*)(o_part + (((size_t)bh * NCHUNK + chunk) * SQ + r) * HD + dq * 4) = O;
        if (dq == 0) {
            ml_part[(((size_t)bh * NCHUNK + chunk) * SQ + r) * 2 + 0] = M;
            ml_part[(((size_t)bh * NCHUNK + chunk) * SQ + r) * 2 + 1] = L;
        }
    }
}

// ---------------------------------------------------------------------------
// Kernel 3: combine partials -> ctx [64][1024]  (unchanged)
// ---------------------------------------------------------------------------
__global__ __launch_bounds__(256) void attn_combine(
    const float* __restrict__ o_part,
    const float* __restrict__ ml_part,
    float* __restrict__ ctx)
{
    __shared__ float mls[NCHUNK * 4 * 2];
    const int bh = blockIdx.x >> 2, qg = blockIdx.x & 3;
    const int b = bh >> 4, h = bh & 15;
    const int t = threadIdx.x;
    const int qi_l = t >> 6, d = t & 63;
    const int qi = qg * 4 + qi_l;

    mls[t] = ml_part[(((size_t)bh * NCHUNK + (t >> 3)) * SQ + qg * 4 + ((t >> 1) & 3)) * 2 + (t & 1)];
    __syncthreads();

    float M = -INFINITY;
    #pragma unroll
    for (int c = 0; c < NCHUNK; ++c) M = fmaxf(M, mls[(c * 4 + qi_l) * 2]);
    float L = 0.f, O = 0.f;
    #pragma unroll 4
    for (int c = 0; c < NCHUNK; ++c) {
        const float sc = __expf(mls[(c * 4 + qi_l) * 2] - M);
        L += mls[(c * 4 + qi_l) * 2 + 1] * sc;
        O += o_part[(((size_t)bh * NCHUNK + c) * SQ + qi) * HD + d] * sc;
    }
    ctx[((size_t)(b * SQ + qi)) * HID + h * HD + d] = O / L;
}

// ---------------------------------------------------------------------------
// Kernel 4: y = x + ctx @ wo^T + bo  (unchanged)
// ---------------------------------------------------------------------------
__global__ __launch_bounds__(256) void out_gemv(
    const float* __restrict__ ctx,
    const float* __restrict__ x,
    const float* __restrict__ wo,
    const float* __restrict__ bo,
    float* __restrict__ y)
{
    __shared__ float xs[ROWS * 256];

    const int t = threadIdx.x, w = t >> 6, l = t & 63;
    const int j = blockIdx.x * 4 + w;

    float acc[ROWS];
    #pragma unroll
    for (int r = 0; r < ROWS; ++r) acc[r] = 0.f;

    const float4* c4 = (const float4*)ctx;
    const float4* w4 = (const float4*)(wo + (size_t)j * HID);
    float4* xs4 = (float4*)xs;

    for (int ck = 0; ck < 4; ++ck) {
        __syncthreads();
        #pragma unroll
        for (int p = 0; p < 16; ++p) {
            const int idx = t + p * 256;
            const int r = idx >> 6, c = idx & 63;
            xs4[idx] = c4[(size_t)r * 256 + ck * 64 + c];
        }
        __syncthreads();

        const float4 wf = w4[ck * 64 + l];
        #pragma unroll
        for (int r = 0; r < ROWS; ++r) {
            const float4 xf = xs4[r * 64 + l];
            acc[r] += wf.x * xf.x + wf.y * xf.y + wf.z * xf.z + wf.w * xf.w;
        }
    }

    #pragma unroll
    for (int r = 0; r < ROWS; ++r) {
        float a = acc[r];
        #pragma unroll
        for (int off = 32; off; off >>= 1) a += __shfl_xor(a, off);
        acc[r] = a;
    }
    float val = acc[0];
    #pragma unroll
    for (int r = 1; r < ROWS; ++r) val = (l == r) ? acc[r] : val;

    val += bo[j] + x[(size_t)l * HID + j];
    y[(size_t)l * HID + j] = val;
}

// ---------------------------------------------------------------------------
// Kernel 5: out = LN(y) * gamma + beta  (unchanged)
// ---------------------------------------------------------------------------
__global__ __launch_bounds__(256) void ln_kernel(
    const float* __restrict__ y,
    const float* __restrict__ gamma,
    const float* __restrict__ beta,
    float* __restrict__ out)
{
    __shared__ float red[8];
    const int r = blockIdx.x, t = threadIdx.x;
    const int w = t >> 6, l = t & 63;

    const float4 yv = ((const float4*)(y + (size_t)r * HID))[t];
    float sum = yv.x + yv.y + yv.z + yv.w;
    float ssq = yv.x * yv.x + yv.y * yv.y + yv.z * yv.z + yv.w * yv.w;
    #pragma unroll
    for (int off = 32; off; off >>= 1) {
        sum += __shfl_xor(sum, off);
        ssq += __shfl_xor(ssq, off);
    }
    if (l == 0) { red[w] = sum; red[4 + w] = ssq; }
    __syncthreads();
    sum = red[0] + red[1] + red[2] + red[3];
    ssq = red[4] + red[5] + red[6] + red[7];
    const float mu = sum * (1.f / HID);
    const float var = ssq * (1.f / HID) - mu * mu;
    const float rstd = rsqrtf(var + LN_EPS);

    const float4 g = ((const float4*)gamma)[t];
    const float4 be = ((const float4*)beta)[t];
    float4 o;
    o.x = (yv.x - mu) * rstd * g.x + be.x;
    o.y = (yv.y - mu) * rstd * g.y + be.y;
    o.z = (yv.z - mu) * rstd * g.z + be.z;
    o.w = (yv.w - mu) * rstd * g.w + be.w;
    ((float4*)(out + (size_t)r * HID))[t] = o;
}

// ---------------------------------------------------------------------------
extern "C" void kernel_launch(void* const* d_in, const int* in_sizes, int n_in,
                              void* d_out, int out_size, void* d_ws, size_t ws_size,
                              hipStream_t stream) {
    const float* x     = (const float*)d_in[0];
    const float* xm    = (const float*)d_in[1];
    const float* kc    = (const float*)d_in[2];
    const float* vc    = (const float*)d_in[3];
    const float* wq    = (const float*)d_in[4];
    const float* bq    = (const float*)d_in[5];
    const float* wo    = (const float*)d_in[6];
    const float* bo    = (const float*)d_in[7];
    const float* gamma = (const float*)d_in[8];
    const float* beta  = (const float*)d_in[9];
    float* out = (float*)d_out;

    float* ws = (float*)d_ws;
    float* q_ws   = ws;                                               // 65536
    float* o_ws   = q_ws + ROWS * HID;                                // 2097152
    float* ml_ws  = o_ws + (size_t)BATCH * NHEADS * NCHUNK * SQ * HD; // 65536
    float* ctx_ws = ml_ws + BATCH * NHEADS * NCHUNK * SQ * 2;         // 65536
    float* y_ws   = ctx_ws + ROWS * HID;                              // 65536

    qrope_gemv<<<dim3(256), 256, 0, stream>>>(x, xm, wq, bq, q_ws);
    attn_partial<<<dim3(NCHUNK, NHEADS, BATCH), 256, 0, stream>>>(q_ws, kc, vc, o_ws, ml_ws);
    attn_combine<<<dim3(256), 256, 0, stream>>>(o_ws, ml_ws, ctx_ws);
    out_gemv<<<dim3(256), 256, 0, stream>>>(ctx_ws, x, wo, bo, y_ws);
    ln_kernel<<<dim3(ROWS), 256, 0, stream>>>(y_ws, gamma, beta, out);
}